// Round 5
// baseline (39.241 us; speedup 1.0000x reference)
//
#include <hip/hip_runtime.h>

#define BS 8
#define NN 1024
#define JJ 4
#define FF 32
#define NC 2

#define CHUNK 256              // m-values per block
#define NCHUNK (NN / CHUNK)    // 4
#define ROWS 16                // output rows per block (4 per wave)
#define THREADS 256

typedef float f4v __attribute__((ext_vector_type(4)));

// out[b,n,c] += sum_{m in chunk} sum_j WW[b,n,m,j] * y[b,m,j,c]  (+ bias once)
// y[b,m,j,c] = sum_f x[b,m,f] * fc_w[c, j*FF+f], computed per-block for its
// 256-m chunk only (1 m per thread, cheap), staged in LDS.
// Grid = 2048 blocks -> ~6-8 resident/CU; prologues overlap other blocks'
// HBM streams. Partials accumulated with atomicAdd (out pre-zeroed).
__global__ void __launch_bounds__(THREADS) fused_atomic_kernel(
    const float* __restrict__ WW, const float* __restrict__ x,
    const float* __restrict__ fc_w, const float* __restrict__ fc_b,
    float* __restrict__ out) {
    __shared__ float4 lyA[CHUNK];  // (j0c0,j0c1,j1c0,j1c1) per m
    __shared__ float4 lyB[CHUNK];  // (j2c0,j2c1,j3c0,j3c1) per m

    const int bid    = blockIdx.x;          // 0..2047
    const int chunk  = bid & (NCHUNK - 1);  // 0..3
    const int rowgrp = bid >> 2;            // 0..511
    const int b      = rowgrp >> 6;         // 64 rowgrps per batch element
    const int m0     = chunk * CHUNK;

    const int tid  = threadIdx.x;
    const int wave = tid >> 6;
    const int lane = tid & 63;

    // ---- prologue: y[b][m0+tid][*] -> LDS (256 FMA/thread) ----
    {
        const float4* xr = reinterpret_cast<const float4*>(
            x + ((size_t)b * NN + m0 + tid) * FF);
        float xv[FF];
#pragma unroll
        for (int q = 0; q < FF / 4; ++q) {
            float4 v = xr[q];
            xv[4 * q + 0] = v.x; xv[4 * q + 1] = v.y;
            xv[4 * q + 2] = v.z; xv[4 * q + 3] = v.w;
        }
        float a[JJ][NC];
#pragma unroll
        for (int j = 0; j < JJ; ++j) {
            float s0 = 0.f, s1 = 0.f;
            const float* w0 = fc_w + 0 * (JJ * FF) + j * FF;  // uniform -> SGPR
            const float* w1 = fc_w + 1 * (JJ * FF) + j * FF;
#pragma unroll
            for (int f = 0; f < FF; ++f) {
                float xf = xv[f];
                s0 += xf * w0[f];
                s1 += xf * w1[f];
            }
            a[j][0] = s0; a[j][1] = s1;
        }
        lyA[tid] = make_float4(a[0][0], a[0][1], a[1][0], a[1][1]);
        lyB[tid] = make_float4(a[2][0], a[2][1], a[3][0], a[3][1]);
    }
    __syncthreads();

    // ---- main: 4 rows per wave over the 256-m chunk ----
    const int row0 = rowgrp * ROWS + wave * 4;  // global row = b*NN + n
    const f4v* Wp = reinterpret_cast<const f4v*>(WW);

    float s[4][2] = {{0.f, 0.f}, {0.f, 0.f}, {0.f, 0.f}, {0.f, 0.f}};
#pragma unroll
    for (int i = 0; i < CHUNK / 64; ++i) {  // 4 iterations
        const int ml = lane + 64 * i;
        const float4 ya = lyA[ml];
        const float4 yb = lyB[ml];
        const size_t base = (size_t)row0 * NN + m0 + ml;
#pragma unroll
        for (int r = 0; r < 4; ++r) {
            f4v w = __builtin_nontemporal_load(Wp + base + (size_t)r * NN);
            s[r][0] += w.x * ya.x + w.y * ya.z + w.z * yb.x + w.w * yb.z;
            s[r][1] += w.x * ya.y + w.y * ya.w + w.z * yb.y + w.w * yb.w;
        }
    }

#pragma unroll
    for (int off = 32; off > 0; off >>= 1) {
#pragma unroll
        for (int r = 0; r < 4; ++r) {
            s[r][0] += __shfl_down(s[r][0], off, 64);
            s[r][1] += __shfl_down(s[r][1], off, 64);
        }
    }
    if (lane == 0) {
        const float b0 = (chunk == 0) ? fc_b[0] : 0.f;
        const float b1 = (chunk == 0) ? fc_b[1] : 0.f;
#pragma unroll
        for (int r = 0; r < 4; ++r) {
            atomicAdd(&out[(size_t)(row0 + r) * NC + 0], s[r][0] + b0);
            atomicAdd(&out[(size_t)(row0 + r) * NC + 1], s[r][1] + b1);
        }
    }
}

extern "C" void kernel_launch(void* const* d_in, const int* in_sizes, int n_in,
                              void* d_out, int out_size, void* d_ws, size_t ws_size,
                              hipStream_t stream) {
    const float* WW   = (const float*)d_in[0];  // (BS, NN, NN, JJ) fp32
    const float* x    = (const float*)d_in[1];  // (BS, NN, FF) fp32
    const float* fc_w = (const float*)d_in[2];  // (NC, JJ*FF) fp32
    const float* fc_b = (const float*)d_in[3];  // (NC,) fp32
    float* out = (float*)d_out;                 // (BS, NN, NC) fp32

    // atomics accumulate -> zero out each call (memset node in the graph)
    hipMemsetAsync(out, 0, (size_t)out_size * sizeof(float), stream);

    const int blocks = (BS * NN / ROWS) * NCHUNK;  // 512 * 4 = 2048
    fused_atomic_kernel<<<blocks, THREADS, 0, stream>>>(WW, x, fc_w, fc_b, out);
}

// Round 6
// 31.459 us; speedup vs baseline: 1.2474x; 1.2474x over previous
//
#include <hip/hip_runtime.h>

#define BS 8
#define NN 1024
#define JJ 4
#define FF 32
#define NC 2

#define ROWS 8       // rows per block (block-exclusive)
#define THREADS 256

typedef float f4v __attribute__((ext_vector_type(4)));

// y[b][m][j][c] = sum_f x[b,m,f] * fc_w[c, j*FF+f]
// Deinterleaved: yA[bm] = (j0c0,j0c1,j1c0,j1c1), yB[bm] = (j2c0,j2c1,j3c0,j3c1)
__global__ void __launch_bounds__(256) compute_y_kernel(
    const float* __restrict__ x, const float* __restrict__ fc_w,
    float2* __restrict__ yA, float2* __restrict__ yB) {
    int idx = blockIdx.x * blockDim.x + threadIdx.x;  // BS*NN*JJ = 32768
    if (idx >= BS * NN * JJ) return;
    int j  = idx & (JJ - 1);
    int bm = idx >> 2;
    const float* xr = x + (size_t)bm * FF;
    const float* w0 = fc_w + 0 * (JJ * FF) + j * FF;
    const float* w1 = fc_w + 1 * (JJ * FF) + j * FF;
    float a0 = 0.f, a1 = 0.f;
#pragma unroll
    for (int f = 0; f < FF; ++f) {
        float xv = xr[f];
        a0 += xv * w0[f];
        a1 += xv * w1[f];
    }
    float2 v = make_float2(a0, a1);
    if (j < 2) yA[bm * 2 + j]       = v;
    else       yB[bm * 2 + (j - 2)] = v;
}

// Each block owns 8 consecutive rows (128 KB contiguous WW span) and walks it
// front-to-back: step k reads one 4 KB slab with all 256 threads (block-linear,
// copy-ubench-shaped). 32 steps/block; per-row shuffle reduce into LDS; final
// write adds bias (rows are block-exclusive -> no atomics, no memset).
__global__ void __launch_bounds__(THREADS, 4) reduce_seq_kernel(
    const float* __restrict__ WW, const float4* __restrict__ yA,
    const float4* __restrict__ yB, const float* __restrict__ fc_b,
    float* __restrict__ out) {
    __shared__ float4 lyA[NN];
    __shared__ float4 lyB[NN];
    __shared__ float2 part[ROWS][4];

    const int tid  = threadIdx.x;
    const int wave = tid >> 6;
    const int lane = tid & 63;
    const int rowbase = blockIdx.x * ROWS;   // global row in [0, BS*NN)
    const int b       = rowbase >> 10;

    // stage y[b] (32 KB) into LDS, coalesced
    for (int i = tid; i < NN; i += THREADS) {
        lyA[i] = yA[(size_t)b * NN + i];
        lyB[i] = yB[(size_t)b * NN + i];
    }
    __syncthreads();

    // block-linear walk: flat float4 index within span = k*256 + tid
    const f4v* Wp = reinterpret_cast<const f4v*>(WW) + (size_t)rowbase * NN;

    float s0 = 0.f, s1 = 0.f;
#pragma unroll
    for (int k = 0; k < 4 * ROWS; ++k) {
        const int m = ((k & 3) << 8) + tid;          // m-index within the row
        f4v w = Wp[(size_t)k * THREADS + tid];       // contiguous 4 KB slab
        float4 ya = lyA[m];
        float4 yb = lyB[m];
        s0 += w.x * ya.x + w.y * ya.z + w.z * yb.x + w.w * yb.z;
        s1 += w.x * ya.y + w.y * ya.w + w.z * yb.y + w.w * yb.w;
        if ((k & 3) == 3) {                          // row finished
#pragma unroll
            for (int off = 32; off > 0; off >>= 1) {
                s0 += __shfl_down(s0, off, 64);
                s1 += __shfl_down(s1, off, 64);
            }
            if (lane == 0) part[k >> 2][wave] = make_float2(s0, s1);
            s0 = 0.f; s1 = 0.f;
        }
    }
    __syncthreads();

    if (tid < ROWS) {
        float2 p0 = part[tid][0], p1 = part[tid][1];
        float2 p2 = part[tid][2], p3 = part[tid][3];
        float2 r;
        r.x = p0.x + p1.x + p2.x + p3.x + fc_b[0];
        r.y = p0.y + p1.y + p2.y + p3.y + fc_b[1];
        reinterpret_cast<float2*>(out)[rowbase + tid] = r;
    }
}

extern "C" void kernel_launch(void* const* d_in, const int* in_sizes, int n_in,
                              void* d_out, int out_size, void* d_ws, size_t ws_size,
                              hipStream_t stream) {
    const float* WW   = (const float*)d_in[0];  // (BS, NN, NN, JJ) fp32
    const float* x    = (const float*)d_in[1];  // (BS, NN, FF) fp32
    const float* fc_w = (const float*)d_in[2];  // (NC, JJ*FF) fp32
    const float* fc_b = (const float*)d_in[3];  // (NC,) fp32
    float* out = (float*)d_out;                 // (BS, NN, NC) fp32

    float* ws   = (float*)d_ws;
    float2* yA2 = (float2*)ws;
    float2* yB2 = (float2*)(ws + (size_t)BS * NN * 4);

    {
        int total = BS * NN * JJ;
        compute_y_kernel<<<(total + 255) / 256, 256, 0, stream>>>(x, fc_w, yA2, yB2);
    }
    {
        int blocks = (BS * NN) / ROWS;  // 1024 blocks, 128 KB WW span each
        reduce_seq_kernel<<<blocks, THREADS, 0, stream>>>(
            WW, (const float4*)yA2, (const float4*)yB2, fc_b, out);
    }
}